// Round 4
// baseline (293.281 us; speedup 1.0000x reference)
//
#include <hip/hip_runtime.h>
#include <math.h>

#define T 2048
#define D 768
#define E 8
#define FF 3072
#define NPOS (2 * T)
#define MAXTILE 40
#define MAXTILE2 72
#define PSTRIDE ((size_t)(NPOS + 64) * D)

using bf16x8 = __attribute__((ext_vector_type(8))) short;
using f32x4  = __attribute__((ext_vector_type(4))) float;
using u16x8  = __attribute__((ext_vector_type(8))) unsigned short;

__device__ __forceinline__ unsigned short f2bf(float f) {
    union { float f; unsigned u; } v; v.f = f;
    unsigned r = v.u + 0x7FFF + ((v.u >> 16) & 1);
    return (unsigned short)(r >> 16);
}
__device__ __forceinline__ float bf2f(unsigned short u) {
    union { unsigned u; float f; } v; v.u = ((unsigned)u) << 16;
    return v.f;
}
__device__ __forceinline__ float siluf(float v) {
    return v / (1.0f + __expf(-v));
}
__device__ __forceinline__ void gload16(const void* g, void* l) {
    __builtin_amdgcn_global_load_lds(
        (const __attribute__((address_space(1))) void*)g,
        (__attribute__((address_space(3))) void*)l, 16, 0, 0);
}

// ---------------------------------------------------------------------------
// Pre-pass: x f32 -> bf16
// ---------------------------------------------------------------------------
__global__ __launch_bounds__(256)
void convert_x_kernel(const float* __restrict__ x, unsigned short* __restrict__ xb) {
    int i = blockIdx.x * 256 + threadIdx.x;
    const float4* p = (const float4*)x + (size_t)i * 2;
    float4 a = p[0], b = p[1];
    u16x8 o;
    o[0] = f2bf(a.x); o[1] = f2bf(a.y); o[2] = f2bf(a.z); o[3] = f2bf(a.w);
    o[4] = f2bf(b.x); o[5] = f2bf(b.y); o[6] = f2bf(b.z); o[7] = f2bf(b.w);
    *((u16x8*)xb + i) = o;
}

// ---------------------------------------------------------------------------
// Pre-pass: transpose+convert  in f32 [E][R][C] -> out bf16 [E][C][R]
// ---------------------------------------------------------------------------
__global__ __launch_bounds__(256)
void transpose_convert(const float* __restrict__ in, unsigned short* __restrict__ out,
                       int R, int C) {
    __shared__ unsigned short tb[64][72];
    int e = blockIdx.z;
    int r0 = blockIdx.y * 64, c0 = blockIdx.x * 64;
    int tid = threadIdx.x;
    const float* ip = in + (size_t)e * R * C;
#pragma unroll
    for (int p = 0; p < 4; ++p) {
        int r = (tid >> 4) + 16 * p;
        int c = (tid & 15) * 4;
        float4 v = *(const float4*)(ip + (size_t)(r0 + r) * C + (c0 + c));
        tb[c + 0][r] = f2bf(v.x);
        tb[c + 1][r] = f2bf(v.y);
        tb[c + 2][r] = f2bf(v.z);
        tb[c + 3][r] = f2bf(v.w);
    }
    __syncthreads();
    unsigned short* op = out + (size_t)e * R * C + (size_t)c0 * R + r0;
    int c = tid >> 2;
    int rs = (tid & 3) * 16;
#pragma unroll
    for (int i = 0; i < 2; ++i) {
        u16x8 w = *(const u16x8*)&tb[c][rs + 8 * i];
        *(u16x8*)(op + (size_t)c * R + rs + 8 * i) = w;
    }
}

// ---------------------------------------------------------------------------
// Router
// ---------------------------------------------------------------------------
__global__ void router_kernel(const float* __restrict__ x,
                              const float* __restrict__ rw,
                              const float* __restrict__ rb,
                              const float* __restrict__ dgw,
                              const float* __restrict__ dgb,
                              int* __restrict__ e_arr,
                              float* __restrict__ s_arr,
                              int* __restrict__ counts) {
    int lane = threadIdx.x & 63;
    int wv = threadIdx.x >> 6;
    int t = blockIdx.x * 4 + wv;
    if (t >= T) return;

    float lg[E], dl[E];
#pragma unroll
    for (int e = 0; e < E; ++e) { lg[e] = 0.f; dl[e] = 0.f; }

    const float* xt = x + (size_t)t * D;
#pragma unroll
    for (int i = 0; i < D / 64; ++i) {
        int d = lane + 64 * i;
        float xv = xt[d];
#pragma unroll
        for (int e = 0; e < E; ++e) {
            lg[e] = fmaf(xv, rw[d * E + e], lg[e]);
            dl[e] = fmaf(xv, dgw[e * D + d], dl[e]);
        }
    }
#pragma unroll
    for (int e = 0; e < E; ++e) {
        for (int off = 32; off; off >>= 1) {
            lg[e] += __shfl_xor(lg[e], off);
            dl[e] += __shfl_xor(dl[e], off);
        }
    }
    if (lane == 0) {
        float p[E];
        float m = -1e30f;
#pragma unroll
        for (int e = 0; e < E; ++e) { lg[e] += rb[e]; m = fmaxf(m, lg[e]); }
        float s = 0.f;
#pragma unroll
        for (int e = 0; e < E; ++e) { p[e] = __expf(lg[e] - m); s += p[e]; }
        float inv = 1.0f / s;
#pragma unroll
        for (int e = 0; e < E; ++e) p[e] *= inv;

        int i0 = 0; float b0 = p[0];
#pragma unroll
        for (int e = 1; e < E; ++e) if (p[e] > b0) { b0 = p[e]; i0 = e; }
        int i1 = -1; float b1 = -1.0f;
#pragma unroll
        for (int e = 0; e < E; ++e) if (e != i0 && p[e] > b1) { b1 = p[e]; i1 = e; }

        float eb = __expf(b1 - b0);
        float w0 = 1.0f / (1.0f + eb);
        float w1 = eb / (1.0f + eb);

        float dg0 = 1.0f / (1.0f + __expf(-(dl[i0] + dgb[i0])));
        float dg1 = 1.0f / (1.0f + __expf(-(dl[i1] + dgb[i1])));

        e_arr[t * 2 + 0] = i0;
        e_arr[t * 2 + 1] = i1;
        s_arr[t * 2 + 0] = dg0 * w0;
        s_arr[t * 2 + 1] = dg1 * w1;
        atomicAdd(&counts[i0], 1);
        atomicAdd(&counts[i1], 1);
    }
}

// ---------------------------------------------------------------------------
// Scan — bases, cursor, expert_load, M-tile lists (128-row and 64-row)
// ---------------------------------------------------------------------------
__global__ void scan_kernel(const int* __restrict__ counts,
                            int* __restrict__ bases,
                            int* __restrict__ cursor,
                            float* __restrict__ load_out,
                            int* __restrict__ tme, int* __restrict__ tmm,
                            int* __restrict__ tml,
                            int* __restrict__ tme2, int* __restrict__ tmm2,
                            int* __restrict__ tml2) {
    if (threadIdx.x == 0 && blockIdx.x == 0) {
        int b = 0, nt = 0, nt2 = 0;
        for (int e = 0; e < E; ++e) {
            int c = counts[e];
            bases[e] = b;
            cursor[e] = b;
            load_out[e] = (float)c;
            for (int m = 0; m < c; m += 128) {
                tme[nt] = e;
                tmm[nt] = b + m;
                tml[nt] = (c - m < 128) ? (c - m) : 128;
                ++nt;
            }
            for (int m = 0; m < c; m += 64) {
                tme2[nt2] = e;
                tmm2[nt2] = b + m;
                tml2[nt2] = (c - m < 64) ? (c - m) : 64;
                ++nt2;
            }
            b += c;
        }
        bases[E] = b;
        for (; nt < MAXTILE; ++nt) tme[nt] = -1;
        for (; nt2 < MAXTILE2; ++nt2) tme2[nt2] = -1;
    }
}

__global__ void assign_kernel(const int* __restrict__ e_arr,
                              int* __restrict__ cursor,
                              int* __restrict__ a_tok,
                              int* __restrict__ pos_of) {
    int t = blockIdx.x * blockDim.x + threadIdx.x;
    if (t >= T) return;
#pragma unroll
    for (int s = 0; s < 2; ++s) {
        int e = e_arr[t * 2 + s];
        int pos = atomicAdd(&cursor[e], 1);
        a_tok[pos] = t;
        pos_of[t * 2 + s] = pos;
    }
}

// ---------------------------------------------------------------------------
// GEMM1: acts[pos][f] = silu(x@w1+b1)*silu(x@w3+b3), bf16.
// Tile 128(M) x 64(F), K=768, BK=64, gload_lds staging, XOR-swizzled LDS.
// ---------------------------------------------------------------------------
__global__ __launch_bounds__(256, 2)
void gemm1_kernel(const unsigned short* __restrict__ xb,
                  const unsigned short* __restrict__ w1t, const float* __restrict__ w1b,
                  const unsigned short* __restrict__ w3t, const float* __restrict__ w3b,
                  const int* __restrict__ a_tok,
                  const int* __restrict__ tme, const int* __restrict__ tmm,
                  const int* __restrict__ tml,
                  unsigned short* __restrict__ acts) {
    int mt = blockIdx.y;
    int e = tme[mt];
    if (e < 0) return;
    int mstart = tmm[mt], mlen = tml[mt];
    int fBase = blockIdx.x * 64;

    __shared__ char As[2][16384];
    __shared__ char Bs[2][16384];   // [0,8K)=w1 tile, [8K,16K)=w3 tile

    int tid = threadIdx.x;
    int lane = tid & 63, wv = tid >> 6;
    int wr = wv & 1, wc = wv >> 1;
    int l15 = lane & 15, lk = lane >> 4;
    int lrow = lane >> 3;
    int swl = (((lane & 7) ^ lrow) << 4);

    const char* xbp = (const char*)xb;
    size_t aoff[4];
#pragma unroll
    for (int i = 0; i < 4; ++i) {
        int r = (wv + 4 * i) * 8 + lrow;
        int rr = r < mlen ? r : mlen - 1;
        aoff[i] = (size_t)a_tok[mstart + rr] * (D * 2) + swl;
    }
    const char* w1p = (const char*)(w1t + (size_t)e * FF * D);
    const char* w3p = (const char*)(w3t + (size_t)e * FF * D);
    size_t boff[2];
#pragma unroll
    for (int i = 0; i < 2; ++i) {
        int f = (wv + 4 * i) * 8 + lrow;
        boff[i] = (size_t)(fBase + f) * (D * 2) + swl;
    }

    auto stage = [&](int buf, int k0) {
        int kb = k0 * 2;
        char* ab = &As[buf][0];
        char* bb = &Bs[buf][0];
#pragma unroll
        for (int i = 0; i < 4; ++i)
            gload16(xbp + aoff[i] + kb, ab + (wv + 4 * i) * 1024);
#pragma unroll
        for (int i = 0; i < 2; ++i) {
            gload16(w1p + boff[i] + kb, bb + (wv + 4 * i) * 1024);
            gload16(w3p + boff[i] + kb, bb + 8192 + (wv + 4 * i) * 1024);
        }
    };

    f32x4 hacc[4][2], gacc[4][2];
#pragma unroll
    for (int m = 0; m < 4; ++m)
#pragma unroll
        for (int n = 0; n < 2; ++n) {
            hacc[m][n] = f32x4{0.f, 0.f, 0.f, 0.f};
            gacc[m][n] = f32x4{0.f, 0.f, 0.f, 0.f};
        }

    stage(0, 0);
    __syncthreads();
    for (int ks = 0; ks < 12; ++ks) {
        int cur = ks & 1;
        if (ks < 11) stage(cur ^ 1, (ks + 1) * 64);
        const char* Ab = &As[cur][0];
        const char* Bb = &Bs[cur][0];
#pragma unroll
        for (int ksub = 0; ksub < 2; ++ksub) {
            int kb = ksub * 64 + lk * 16;
            bf16x8 af[4];
#pragma unroll
            for (int m = 0; m < 4; ++m) {
                int row = wr * 64 + m * 16 + l15;
                af[m] = *(const bf16x8*)(Ab + row * 128 + (kb ^ ((row & 7) << 4)));
            }
#pragma unroll
            for (int n = 0; n < 2; ++n) {
                int rowf = wc * 32 + n * 16 + l15;
                int off = rowf * 128 + (kb ^ ((rowf & 7) << 4));
                bf16x8 b1 = *(const bf16x8*)(Bb + off);
                bf16x8 b3 = *(const bf16x8*)(Bb + 8192 + off);
#pragma unroll
                for (int m = 0; m < 4; ++m) {
                    hacc[m][n] = __builtin_amdgcn_mfma_f32_16x16x32_bf16(af[m], b1, hacc[m][n], 0, 0, 0);
                    gacc[m][n] = __builtin_amdgcn_mfma_f32_16x16x32_bf16(af[m], b3, gacc[m][n], 0, 0, 0);
                }
            }
        }
        __syncthreads();
    }

    // epilogue: silu(h)*silu(g) -> bf16 tile in LDS -> vectorized store
    unsigned short* al = (unsigned short*)&As[0][0];
    float b1v[2], b3v[2];
#pragma unroll
    for (int n = 0; n < 2; ++n) {
        int f = fBase + wc * 32 + n * 16 + l15;
        b1v[n] = w1b[e * FF + f];
        b3v[n] = w3b[e * FF + f];
    }
#pragma unroll
    for (int m = 0; m < 4; ++m)
#pragma unroll
        for (int n = 0; n < 2; ++n)
#pragma unroll
            for (int j = 0; j < 4; ++j) {
                float h = hacc[m][n][j] + b1v[n];
                float g = gacc[m][n][j] + b3v[n];
                int row = wr * 64 + m * 16 + lk * 4 + j;
                int col = wc * 32 + n * 16 + l15;
                al[row * 64 + col] = f2bf(siluf(h) * siluf(g));
            }
    __syncthreads();
    int r = tid >> 1, cb = (tid & 1) * 32;
    if (r < mlen) {
        unsigned short* gp = acts + (size_t)(mstart + r) * FF + fBase + cb;
        const unsigned short* lp = al + r * 64 + cb;
#pragma unroll
        for (int i = 0; i < 4; ++i)
            *(u16x8*)(gp + i * 8) = *(const u16x8*)(lp + i * 8);
    }
}

// ---------------------------------------------------------------------------
// GEMM2: ffs_part[ksl][pos][d] = acts[pos][kslice] @ w2[kslice].
// Tile 64(M) x 128(N), split-K=2 (K=1536 each, 24 steps). 48KB LDS, 3/CU.
// ---------------------------------------------------------------------------
__global__ __launch_bounds__(256, 3)
void gemm2_kernel(const unsigned short* __restrict__ acts,
                  const unsigned short* __restrict__ w2t,
                  const int* __restrict__ tme2, const int* __restrict__ tmm2,
                  const int* __restrict__ tml2,
                  float* __restrict__ ffs) {
    int mt = blockIdx.y;
    int e = tme2[mt];
    if (e < 0) return;
    int mstart = tmm2[mt], mlen = tml2[mt];
    int nBase = blockIdx.x * 128;
    int ksl = blockIdx.z;

    __shared__ char As[2][8192];
    __shared__ char Bs[2][16384];

    int tid = threadIdx.x;
    int lane = tid & 63, wv = tid >> 6;
    int wr = wv & 1, wc = wv >> 1;
    int l15 = lane & 15, lk = lane >> 4;
    int lrow = lane >> 3;
    int swl = (((lane & 7) ^ lrow) << 4);

    const char* ap = (const char*)acts;
    const char* w2p = (const char*)(w2t + (size_t)e * (size_t)D * FF);
    size_t aoff[2], boff[4];
#pragma unroll
    for (int i = 0; i < 2; ++i) {
        int r = (wv + 4 * i) * 8 + lrow;
        aoff[i] = (size_t)(mstart + r) * (FF * 2) + swl;
    }
#pragma unroll
    for (int i = 0; i < 4; ++i) {
        int r = (wv + 4 * i) * 8 + lrow;
        boff[i] = (size_t)(nBase + r) * (FF * 2) + swl;
    }
    int kOff = ksl * (FF / 2) * 2;   // byte offset of this K slice

    auto stage = [&](int buf, int k0) {
        int kb = kOff + k0 * 2;
        char* ab = &As[buf][0];
        char* bb = &Bs[buf][0];
#pragma unroll
        for (int i = 0; i < 2; ++i)
            gload16(ap + aoff[i] + kb, ab + (wv + 4 * i) * 1024);
#pragma unroll
        for (int i = 0; i < 4; ++i)
            gload16(w2p + boff[i] + kb, bb + (wv + 4 * i) * 1024);
    };

    f32x4 facc[2][4];
#pragma unroll
    for (int m = 0; m < 2; ++m)
#pragma unroll
        for (int n = 0; n < 4; ++n) facc[m][n] = f32x4{0.f, 0.f, 0.f, 0.f};

    stage(0, 0);
    __syncthreads();
    for (int ks = 0; ks < 24; ++ks) {
        int cur = ks & 1;
        if (ks < 23) stage(cur ^ 1, (ks + 1) * 64);
        const char* Ab = &As[cur][0];
        const char* Bb = &Bs[cur][0];
#pragma unroll
        for (int ksub = 0; ksub < 2; ++ksub) {
            int kb = ksub * 64 + lk * 16;
            bf16x8 af[2], bf[4];
#pragma unroll
            for (int m = 0; m < 2; ++m) {
                int row = wr * 32 + m * 16 + l15;
                af[m] = *(const bf16x8*)(Ab + row * 128 + (kb ^ ((row & 7) << 4)));
            }
#pragma unroll
            for (int n = 0; n < 4; ++n) {
                int row = wc * 64 + n * 16 + l15;
                bf[n] = *(const bf16x8*)(Bb + row * 128 + (kb ^ ((row & 7) << 4)));
            }
#pragma unroll
            for (int m = 0; m < 2; ++m)
#pragma unroll
                for (int n = 0; n < 4; ++n)
                    facc[m][n] = __builtin_amdgcn_mfma_f32_16x16x32_bf16(af[m], bf[n], facc[m][n], 0, 0, 0);
        }
        __syncthreads();
    }

    float* op = ffs + (size_t)ksl * PSTRIDE;
#pragma unroll
    for (int m = 0; m < 2; ++m)
#pragma unroll
        for (int j = 0; j < 4; ++j) {
            int row = wr * 32 + m * 16 + lk * 4 + j;
            if (row < mlen) {
                float* gp = op + (size_t)(mstart + row) * D + nBase + wc * 64;
#pragma unroll
                for (int n = 0; n < 4; ++n)
                    gp[n * 16 + l15] = facc[m][n][j];
            }
        }
}

// ---------------------------------------------------------------------------
// Combine — f = part0 + part1 + w2b; y = x + s*f per slot; dual LN; sum; out
// ---------------------------------------------------------------------------
__global__ __launch_bounds__(256)
void combine_kernel(const float* __restrict__ x,
                    const float* __restrict__ ffs,
                    const int* __restrict__ e_arr,
                    const int* __restrict__ pos_of,
                    const float* __restrict__ s_arr,
                    const float* __restrict__ w2b,
                    const float* __restrict__ lng,
                    const float* __restrict__ lnb,
                    float* __restrict__ out) {
    int t = blockIdx.x;
    int tid = threadIdx.x;
    int p0 = pos_of[t * 2], p1 = pos_of[t * 2 + 1];
    int e0 = e_arr[t * 2], e1 = e_arr[t * 2 + 1];
    float sw0 = s_arr[t * 2], sw1 = s_arr[t * 2 + 1];
    __shared__ float red[4][4];

    float y0[3], y1[3];
    float s0 = 0.f, q0 = 0.f, s1 = 0.f, q1 = 0.f;
#pragma unroll
    for (int m = 0; m < 3; ++m) {
        int d = tid + 256 * m;
        float xv = x[(size_t)t * D + d];
        float f0 = ffs[(size_t)p0 * D + d] + ffs[PSTRIDE + (size_t)p0 * D + d] + w2b[e0 * D + d];
        float f1 = ffs[(size_t)p1 * D + d] + ffs[PSTRIDE + (size_t)p1 * D + d] + w2b[e1 * D + d];
        float a = xv + sw0 * f0;
        float bb = xv + sw1 * f1;
        y0[m] = a; y1[m] = bb;
        s0 += a; q0 += a * a;
        s1 += bb; q1 += bb * bb;
    }
    for (int off = 32; off; off >>= 1) {
        s0 += __shfl_xor(s0, off);
        q0 += __shfl_xor(q0, off);
        s1 += __shfl_xor(s1, off);
        q1 += __shfl_xor(q1, off);
    }
    int wv = tid >> 6, lane = tid & 63;
    if (lane == 0) { red[wv][0] = s0; red[wv][1] = q0; red[wv][2] = s1; red[wv][3] = q1; }
    __syncthreads();
    s0 = red[0][0] + red[1][0] + red[2][0] + red[3][0];
    q0 = red[0][1] + red[1][1] + red[2][1] + red[3][1];
    s1 = red[0][2] + red[1][2] + red[2][2] + red[3][2];
    q1 = red[0][3] + red[1][3] + red[2][3] + red[3][3];

    const float invD = 1.0f / (float)D;
    float mu0 = s0 * invD, var0 = q0 * invD - mu0 * mu0;
    float mu1 = s1 * invD, var1 = q1 * invD - mu1 * mu1;
    float r0 = rsqrtf(var0 + 1e-5f);
    float r1 = rsqrtf(var1 + 1e-5f);

#pragma unroll
    for (int m = 0; m < 3; ++m) {
        int d = tid + 256 * m;
        out[(size_t)t * D + d] =
            (y0[m] - mu0) * r0 * lng[e0 * D + d] + lnb[e0 * D + d] +
            (y1[m] - mu1) * r1 * lng[e1 * D + d] + lnb[e1 * D + d];
    }
}

// ---------------------------------------------------------------------------
extern "C" void kernel_launch(void* const* d_in, const int* in_sizes, int n_in,
                              void* d_out, int out_size, void* d_ws, size_t ws_size,
                              hipStream_t stream) {
    const float* x   = (const float*)d_in[0];
    const float* rw  = (const float*)d_in[1];
    const float* rb  = (const float*)d_in[2];
    const float* dgw = (const float*)d_in[3];
    const float* dgb = (const float*)d_in[4];
    const float* w1  = (const float*)d_in[5];
    const float* w1b = (const float*)d_in[6];
    const float* w2  = (const float*)d_in[7];
    const float* w2b = (const float*)d_in[8];
    const float* w3  = (const float*)d_in[9];
    const float* w3b = (const float*)d_in[10];
    const float* lng = (const float*)d_in[11];
    const float* lnb = (const float*)d_in[12];

    float* out = (float*)d_out;
    float* load_out = out + (size_t)T * D;

    char* w = (char*)d_ws;
    size_t off = 0;
    auto alloc = [&](size_t bytes) -> void* {
        void* p = w + off;
        off = (off + bytes + 255) & ~(size_t)255;
        return p;
    };
    int* counts   = (int*)alloc(8 * sizeof(int));
    int* bases    = (int*)alloc(9 * sizeof(int));
    int* cursor   = (int*)alloc(8 * sizeof(int));
    int* e_arr    = (int*)alloc(NPOS * sizeof(int));
    int* a_tok    = (int*)alloc(NPOS * sizeof(int));
    int* pos_of   = (int*)alloc(NPOS * sizeof(int));
    float* s_arr  = (float*)alloc(NPOS * sizeof(float));
    int* tme      = (int*)alloc(MAXTILE * sizeof(int));
    int* tmm      = (int*)alloc(MAXTILE * sizeof(int));
    int* tml      = (int*)alloc(MAXTILE * sizeof(int));
    int* tme2     = (int*)alloc(MAXTILE2 * sizeof(int));
    int* tmm2     = (int*)alloc(MAXTILE2 * sizeof(int));
    int* tml2     = (int*)alloc(MAXTILE2 * sizeof(int));
    unsigned short* xb  = (unsigned short*)alloc((size_t)T * D * 2);
    unsigned short* w1t = (unsigned short*)alloc((size_t)E * D * FF * 2);
    unsigned short* w3t = (unsigned short*)alloc((size_t)E * D * FF * 2);
    unsigned short* w2t = (unsigned short*)alloc((size_t)E * D * FF * 2);
    unsigned short* acts = (unsigned short*)alloc((size_t)(NPOS + 128) * FF * 2);
    float* ffs    = (float*)alloc(2 * PSTRIDE * sizeof(float));

    hipMemsetAsync(counts, 0, 8 * sizeof(int), stream);
    convert_x_kernel<<<(T * D / 8) / 256, 256, 0, stream>>>(x, xb);
    transpose_convert<<<dim3(FF / 64, D / 64, E), 256, 0, stream>>>(w1, w1t, D, FF);
    transpose_convert<<<dim3(FF / 64, D / 64, E), 256, 0, stream>>>(w3, w3t, D, FF);
    transpose_convert<<<dim3(D / 64, FF / 64, E), 256, 0, stream>>>(w2, w2t, FF, D);
    router_kernel<<<T / 4, 256, 0, stream>>>(x, rw, rb, dgw, dgb, e_arr, s_arr, counts);
    scan_kernel<<<1, 64, 0, stream>>>(counts, bases, cursor, load_out,
                                      tme, tmm, tml, tme2, tmm2, tml2);
    assign_kernel<<<(T + 255) / 256, 256, 0, stream>>>(e_arr, cursor, a_tok, pos_of);
    gemm1_kernel<<<dim3(FF / 64, MAXTILE), 256, 0, stream>>>(
        xb, w1t, w1b, w3t, w3b, a_tok, tme, tmm, tml, acts);
    gemm2_kernel<<<dim3(D / 128, MAXTILE2, 2), 256, 0, stream>>>(
        acts, w2t, tme2, tmm2, tml2, ffs);
    combine_kernel<<<T, 256, 0, stream>>>(x, ffs, e_arr, pos_of, s_arr, w2b, lng, lnb, out);
}